// Round 2
// baseline (453.221 us; speedup 1.0000x reference)
//
#include <hip/hip_runtime.h>
#include <hip/hip_fp16.h>

#define N_NODES 50000
#define N_EDGES 1600000
#define D_IN    128
#define D_HID   50
#define D_OUT   10
#define K_CHEB  5

#define WH_ELEMS  (K_CHEB * 64 * D_IN)    // 40960 halfs (W^T, n padded to 64)
#define WH_BLOCKS ((WH_ELEMS + 255) / 256)        // 160
#define XH_BLOCKS (N_NODES * D_IN / 8 / 256)      // 3125 (exact)

#define HIST_BLOCKS 1250                  // 1250 * 1280 = 1.6M exact
#define HIST_EPB    1280

#define DEG_PAD   50048                   // 782 * 64 (scan chunking)
#define SCAN_T    782

#define SC_EPB    1024                    // edges per scatter block (4/thread)
#define SC_BLOCKS ((N_EDGES + SC_EPB - 1) / SC_EPB)   // 1563
#define DN_BLOCKS ((N_NODES + 255) / 256)             // 196

#define VROW      64                      // padded hidden row (halfs) = 128 B
#define VSTRIDE   ((size_t)(N_NODES + 1) * VROW)  // +1 zeroed pad row

#define NGROUP    (N_NODES / 16)          // 3125 node groups (exact)
#define VG_SPAN   512                     // waves per term
#define VG_WAVES  (K_CHEB * VG_SPAN)      // 2560 waves
#define VG_BLOCKS (VG_WAVES / 4)          // 640 blocks x 4 waves

typedef _Float16 half8_t __attribute__((ext_vector_type(8)));
typedef float    f32x4_t __attribute__((ext_vector_type(4)));

// R18: the strip-sort CSR build (pass1 scatter 40us + pass2 41us, both
// latency-bound at <20% of every pipe: 256/196 blocks, serial per-thread
// chains) is replaced by the atomic 3-step build:
//   deg histogram (global atomics, fused into prep) -> 1-block scan
//   (row_start + cursor) -> direct scatter pos=atomicAdd(cursor[r]) fused
//   with vgemm + dinv writers. Edge order per row becomes arbitrary (it
//   already was). Clenshaw/props/final unchanged from R17.

// ---------------- prep: xh convert + Wh build + pad clears + deg histogram ----
__global__ __launch_bounds__(256) void prep_kernel(const float* __restrict__ x,
                                                   const float* __restrict__ W,
                                                   const int* __restrict__ row,
                                                   __half* __restrict__ xh,
                                                   __half* __restrict__ Wh,
                                                   __half* __restrict__ u,
                                                   __half* __restrict__ b1,
                                                   __half* __restrict__ b3,
                                                   __half* __restrict__ b2,
                                                   float* __restrict__ dinv,
                                                   int* __restrict__ deg) {
    int tid = threadIdx.x;
    int blk = blockIdx.x;
    if (blk < XH_BLOCKS) {                // x (fp32) -> xh (fp16), 8 elems/thread
        size_t base = ((size_t)blk * 256 + tid) * 8;
        float4 a = *(const float4*)(x + base);
        float4 b = *(const float4*)(x + base + 4);
        half8_t h;
        h[0] = (_Float16)a.x; h[1] = (_Float16)a.y;
        h[2] = (_Float16)a.z; h[3] = (_Float16)a.w;
        h[4] = (_Float16)b.x; h[5] = (_Float16)b.y;
        h[6] = (_Float16)b.z; h[7] = (_Float16)b.w;
        *(half8_t*)(xh + base) = h;
    } else if (blk < XH_BLOCKS + WH_BLOCKS) {  // Wh = fp16 W^T padded: [t][n<64][i<128]
        int idx = (blk - XH_BLOCKS) * 256 + tid;
        if (idx < WH_ELEMS) {
            int i = idx & 127;
            int n = (idx >> 7) & 63;
            int t = idx >> 13;
            float vv = (n < D_HID) ? W[t * D_IN * D_HID + i * D_HID + n] : 0.f;
            Wh[idx] = __float2half(vv);
        }
    } else if (blk == XH_BLOCKS + WH_BLOCKS) { // zero all gather-target pad rows
        if (tid < VROW) {
            __half z = __float2half(0.f);
            u[4 * VSTRIDE + (size_t)N_NODES * VROW + tid] = z;   // u4 pad
            b1[(size_t)N_NODES * VROW + tid] = z;
            b3[(size_t)N_NODES * VROW + tid] = z;
            b2[(size_t)N_NODES * VROW + tid] = z;
        }
        if (tid == 64) dinv[N_NODES] = 0.f;   // pad entry read by masked lanes
    } else {                              // degree histogram (deg pre-zeroed)
        int hb = blk - (XH_BLOCKS + WH_BLOCKS + 1);
        int base = hb * HIST_EPB;
        for (int i = tid; i < HIST_EPB; i += 256)
            atomicAdd(&deg[row[base + i]], 1);
    }
}

// ---------------- scan: row_start = exclusive prefix(deg); cursor = copy ----
__global__ __launch_bounds__(1024) void scan_kernel(const int* __restrict__ deg,
                                                    int* __restrict__ row_start,
                                                    int* __restrict__ cursor) {
    __shared__ int part[1024];
    int tid = threadIdx.x;
    int sum = 0;
    if (tid < SCAN_T) {
        const uint4* d4 = (const uint4*)deg + (size_t)tid * 16;
        #pragma unroll
        for (int i = 0; i < 16; ++i) {
            uint4 v = d4[i];
            sum += (int)v.x + (int)v.y + (int)v.z + (int)v.w;
        }
    }
    part[tid] = sum;
    __syncthreads();
    for (int o = 1; o < 1024; o <<= 1) {
        int v = (tid >= o) ? part[tid - o] : 0;
        __syncthreads();
        part[tid] += v;
        __syncthreads();
    }
    if (tid < SCAN_T) {
        int run = (tid == 0) ? 0 : part[tid - 1];
        const uint4* d4 = (const uint4*)deg + (size_t)tid * 16;
        uint4* rs4 = (uint4*)row_start + (size_t)tid * 16;
        uint4* cu4 = (uint4*)cursor + (size_t)tid * 16;
        int ng = (tid == SCAN_T - 1) ? 4 : 16;   // last chunk: 16 real nodes
        for (int i = 0; i < ng; ++i) {
            uint4 v = d4[i];
            uint4 o4;
            o4.x = (unsigned)run; run += (int)v.x;
            o4.y = (unsigned)run; run += (int)v.y;
            o4.z = (unsigned)run; run += (int)v.z;
            o4.w = (unsigned)run; run += (int)v.w;
            rs4[i] = o4;
            cu4[i] = o4;
        }
    }
    if (tid == 0) row_start[N_NODES] = part[1023];
}

// -------- fused: vgemm (0..639) + edge scatter (640..2202) + dinv (2203..) ----
__global__ __launch_bounds__(256) void fused_kernel(const int* __restrict__ row,
                                                    const int* __restrict__ col,
                                                    int* __restrict__ cursor,
                                                    int* __restrict__ ewc,
                                                    const __half* __restrict__ xh,
                                                    const __half* __restrict__ Wh,
                                                    __half* __restrict__ u,
                                                    const int* __restrict__ deg,
                                                    float* __restrict__ dinv,
                                                    float* __restrict__ dinv2,
                                                    float* __restrict__ sdeg) {
    int tid = threadIdx.x;
    int blk = blockIdx.x;
    if (blk < VG_BLOCKS) {
        int lane = tid & 63;
        int wv = __builtin_amdgcn_readfirstlane(tid >> 6);
        int w = blk * 4 + wv;             // 0..2559; 512%4==0 -> t uniform per block
        int t = w / VG_SPAN;              // 0..4
        int idx = w - t * VG_SPAN;        // 0..511
        int m = lane & 15;                // node within group (B n-index)
        int quad = lane >> 4;             // k-quad

        const __half* Wt = Wh + t * (64 * D_IN);
        half8_t afr[4][4];                // persistent A-frags (64 VGPRs)
        #pragma unroll
        for (int ks = 0; ks < 4; ++ks) {
            int ko = ks * 32 + quad * 8;
            #pragma unroll
            for (int jt = 0; jt < 4; ++jt)
                afr[ks][jt] = *(const half8_t*)(Wt + (jt * 16 + m) * D_IN + ko);
        }

        __half* ut = u + t * VSTRIDE;

        half8_t pf[4];
        int g = idx;
        {
            const __half* xr = xh + (size_t)(g * 16 + m) * D_IN;
            #pragma unroll
            for (int ks = 0; ks < 4; ++ks)
                pf[ks] = *(const half8_t*)(xr + ks * 32 + quad * 8);
        }

        for (; g < NGROUP; g += VG_SPAN) {
            int node = g * 16 + m;
            half8_t bfr[4];
            #pragma unroll
            for (int ks = 0; ks < 4; ++ks) bfr[ks] = pf[ks];
            int gn = g + VG_SPAN;
            if (gn < NGROUP) {            // prefetch next group's x while MFMAs run
                const __half* xr = xh + (size_t)(gn * 16 + m) * D_IN;
                #pragma unroll
                for (int ks = 0; ks < 4; ++ks)
                    pf[ks] = *(const half8_t*)(xr + ks * 32 + quad * 8);
            }
            f32x4_t acc[4];
            #pragma unroll
            for (int jt = 0; jt < 4; ++jt) acc[jt] = (f32x4_t)0.f;
            #pragma unroll
            for (int ks = 0; ks < 4; ++ks)
                #pragma unroll
                for (int jt = 0; jt < 4; ++jt)
                    acc[jt] = __builtin_amdgcn_mfma_f32_16x16x32_f16(afr[ks][jt], bfr[ks], acc[jt], 0, 0, 0);
            __half* dst = ut + (size_t)node * VROW + quad * 4;
            #pragma unroll
            for (int jt = 0; jt < 4; ++jt) {
                __half2 h0 = __float22half2_rn(make_float2(acc[jt][0], acc[jt][1]));
                __half2 h1 = __float22half2_rn(make_float2(acc[jt][2], acc[jt][3]));
                uint2 uu;
                uu.x = *(unsigned int*)&h0;
                uu.y = *(unsigned int*)&h1;
                *(uint2*)(dst + jt * 16) = uu;
            }
        }
        return;
    }
    if (blk < VG_BLOCKS + SC_BLOCKS) {    // ---- edge scatter into CSR ----
        int sb = blk - VG_BLOCKS;
        int base = sb * SC_EPB;
        #pragma unroll
        for (int i = 0; i < SC_EPB / 256; ++i) {
            int e = base + i * 256 + tid;
            if (e < N_EDGES) {
                int r = row[e];
                int c = col[e];
                int pos = atomicAdd(&cursor[r], 1);
                ewc[pos] = c;
            }
        }
        return;
    }
    // ---- dinv/dinv2/sdeg from deg ----
    int node = (blk - VG_BLOCKS - SC_BLOCKS) * 256 + tid;
    if (node < N_NODES) {
        int d = deg[node];
        float fd = (float)d;
        dinv[node]  = d ? rsqrtf(fd) : 0.f;
        dinv2[node] = d ? (1.f / fd) : 0.f;
        sdeg[node]  = d ? sqrtf(fd)  : 0.f;
    }
}

// ---------------- Clenshaw SpMM step in hidden space ----------------
// dst[r] = dinv[r]*addv[r] + (-alphaM*dinv2[r]) * sum_{c in N(r)} sc(c)*src[c]
//          - DO_SUB * (SCALE_SUB ? dinv[r] : 1) * subv[r]
// sc(c) = SCALE_SRC ? dinv[c] : 1. addv is always u-space (scaled by dinv[r]).
// 1 wave/row; 8 lanes x 16 B cover the 128 B row; 8 edges per gather inst.
template<int SCALE_SRC, int DO_SUB, int SCALE_SUB>
__global__ __launch_bounds__(512) void prop_kernel(const int* __restrict__ row_start,
                                                   const int* __restrict__ ewc,
                                                   const float* __restrict__ dinv2,
                                                   const float* __restrict__ dinv,
                                                   const __half* __restrict__ src,
                                                   const __half* __restrict__ addv,
                                                   const __half* __restrict__ subv,
                                                   float alphaM,
                                                   __half* __restrict__ dst) {
    int tid = threadIdx.x;
    int lane = tid & 63;
    int wv = __builtin_amdgcn_readfirstlane(tid >> 6);  // 0..7
    int r = blockIdx.x * 8 + wv;                        // 6250*8 == 50000
    int e0 = row_start[r], e1 = row_start[r + 1];
    float fac = -alphaM * dinv2[r];
    int l = lane & 7;            // uint4 unit within row (8 x 16 B = 128 B)
    int g = lane >> 3;           // edge slot 0..7
    const uint4* src16 = (const uint4*)src;   // row stride 8 uint4
    float ac[8];
    #pragma unroll
    for (int j = 0; j < 8; ++j) ac[j] = 0.f;
    for (int e = e0; e < e1; e += 32) {
        #pragma unroll
        for (int i = 0; i < 4; ++i) {
            int base = e + 8 * i;
            int cl = ewc[base + g];              // per-lane load, 1 line / instr
            if (base + g >= e1) cl = N_NODES;    // zeroed pad row (dinv[N]=0 too)
            uint4 uu = src16[(size_t)cl * 8 + l];
            float2 f0 = __half22float2(*(__half2*)&uu.x);
            float2 f1 = __half22float2(*(__half2*)&uu.y);
            float2 f2 = __half22float2(*(__half2*)&uu.z);
            float2 f3 = __half22float2(*(__half2*)&uu.w);
            if (SCALE_SRC) {
                float dc = dinv[cl];             // broadcast within 8-lane group
                ac[0] = fmaf(dc, f0.x, ac[0]); ac[1] = fmaf(dc, f0.y, ac[1]);
                ac[2] = fmaf(dc, f1.x, ac[2]); ac[3] = fmaf(dc, f1.y, ac[3]);
                ac[4] = fmaf(dc, f2.x, ac[4]); ac[5] = fmaf(dc, f2.y, ac[5]);
                ac[6] = fmaf(dc, f3.x, ac[6]); ac[7] = fmaf(dc, f3.y, ac[7]);
            } else {
                ac[0] += f0.x; ac[1] += f0.y; ac[2] += f1.x; ac[3] += f1.y;
                ac[4] += f2.x; ac[5] += f2.y; ac[6] += f3.x; ac[7] += f3.y;
            }
        }
    }
    // reduce across the 8 edge slots (lane bits 3,4,5)
    #pragma unroll
    for (int k = 8; k <= 32; k <<= 1) {
        #pragma unroll
        for (int j = 0; j < 8; ++j) ac[j] += __shfl_xor(ac[j], k);
    }
    if (g == 0) {
        float sa = dinv[r];              // addv always u-space
        size_t o = (size_t)r * 8 + l;    // uint4 index
        uint4 av = ((const uint4*)addv)[o];
        float2 av0 = __half22float2(*(__half2*)&av.x);
        float2 av1 = __half22float2(*(__half2*)&av.y);
        float2 av2 = __half22float2(*(__half2*)&av.z);
        float2 av3 = __half22float2(*(__half2*)&av.w);
        float r0 = fmaf(sa, av0.x, fac * ac[0]);
        float r1 = fmaf(sa, av0.y, fac * ac[1]);
        float r2 = fmaf(sa, av1.x, fac * ac[2]);
        float r3 = fmaf(sa, av1.y, fac * ac[3]);
        float r4 = fmaf(sa, av2.x, fac * ac[4]);
        float r5 = fmaf(sa, av2.y, fac * ac[5]);
        float r6 = fmaf(sa, av3.x, fac * ac[6]);
        float r7 = fmaf(sa, av3.y, fac * ac[7]);
        if (DO_SUB) {
            float ss = SCALE_SUB ? dinv[r] : 1.f;
            uint4 sv = ((const uint4*)subv)[o];
            float2 sv0 = __half22float2(*(__half2*)&sv.x);
            float2 sv1 = __half22float2(*(__half2*)&sv.y);
            float2 sv2 = __half22float2(*(__half2*)&sv.z);
            float2 sv3 = __half22float2(*(__half2*)&sv.w);
            r0 = fmaf(-ss, sv0.x, r0); r1 = fmaf(-ss, sv0.y, r1);
            r2 = fmaf(-ss, sv1.x, r2); r3 = fmaf(-ss, sv1.y, r3);
            r4 = fmaf(-ss, sv2.x, r4); r5 = fmaf(-ss, sv2.y, r5);
            r6 = fmaf(-ss, sv3.x, r6); r7 = fmaf(-ss, sv3.y, r7);
        }
        __half2 h0 = __float22half2_rn(make_float2(r0, r1));
        __half2 h1 = __float22half2_rn(make_float2(r2, r3));
        __half2 h2 = __float22half2_rn(make_float2(r4, r5));
        __half2 h3 = __float22half2_rn(make_float2(r6, r7));
        uint4 uu;
        uu.x = *(unsigned int*)&h0;
        uu.y = *(unsigned int*)&h1;
        uu.z = *(unsigned int*)&h2;
        uu.w = *(unsigned int*)&h3;
        ((uint4*)dst)[o] = uu;
    }
}

// ---------------- epilogue: relu(sdeg*S + bias) -> FC -> log_softmax ----------------
__global__ __launch_bounds__(256) void final_kernel(const __half* __restrict__ S,
                                                    const float* __restrict__ sdeg,
                                                    const float* __restrict__ cheb_b,
                                                    const float* __restrict__ fc_w,
                                                    const float* __restrict__ fc_b,
                                                    float* __restrict__ out) {
    int r = blockIdx.x * blockDim.x + threadIdx.x;
    if (r >= N_NODES) return;
    float sc = sdeg[r];
    const __half2* s2 = (const __half2*)(S + (size_t)r * VROW);
    float h[D_HID];
    #pragma unroll
    for (int i = 0; i < D_HID / 2; ++i) {
        float2 f = __half22float2(s2[i]);
        float v0 = sc * f.x + cheb_b[2 * i];
        float v1 = sc * f.y + cheb_b[2 * i + 1];
        h[2 * i]     = v0 > 0.f ? v0 : 0.f;
        h[2 * i + 1] = v1 > 0.f ? v1 : 0.f;
    }
    float lg[D_OUT];
    #pragma unroll
    for (int o = 0; o < D_OUT; ++o) lg[o] = fc_b[o];
    #pragma unroll 2
    for (int i = 0; i < D_HID; ++i) {
        float hv = h[i];
        #pragma unroll
        for (int o = 0; o < D_OUT; ++o) lg[o] += hv * fc_w[i * D_OUT + o];
    }
    float mx = lg[0];
    #pragma unroll
    for (int o = 1; o < D_OUT; ++o) mx = fmaxf(mx, lg[o]);
    float s = 0.f;
    #pragma unroll
    for (int o = 0; o < D_OUT; ++o) s += __expf(lg[o] - mx);
    float ls = __logf(s);
    size_t oo = (size_t)r * D_OUT;
    #pragma unroll
    for (int o = 0; o < D_OUT; ++o) out[oo + o] = lg[o] - mx - ls;
}

extern "C" void kernel_launch(void* const* d_in, const int* in_sizes, int n_in,
                              void* d_out, int out_size, void* d_ws, size_t ws_size,
                              hipStream_t stream) {
    const float* x      = (const float*)d_in[0];
    const int*   edge   = (const int*)d_in[1];
    const float* cheb_w = (const float*)d_in[2];
    const float* cheb_b = (const float*)d_in[3];
    const float* fc_w   = (const float*)d_in[4];
    const float* fc_b   = (const float*)d_in[5];
    float* out = (float*)d_out;

    const int* erow = edge;
    const int* ecol = edge + N_EDGES;

    uintptr_t p = ((uintptr_t)d_ws + 255) & ~(uintptr_t)255;
    auto alloc = [&](size_t bytes) {
        uintptr_t q = p;
        p = (p + bytes + 255) & ~(uintptr_t)255;
        return (void*)q;
    };
    int*    deg       = (int*)alloc((size_t)DEG_PAD * 4);           // zeroed below
    int*    cursor    = (int*)alloc((size_t)N_NODES * 4);
    int*    row_start = (int*)alloc((size_t)(N_NODES + 1) * 4);
    float*  dinv      = (float*)alloc((size_t)(N_NODES + 1) * 4);   // +1 pad (=0)
    float*  dinv2     = (float*)alloc((size_t)N_NODES * 4);
    float*  sdeg      = (float*)alloc((size_t)N_NODES * 4);
    int*    ewc       = (int*)alloc((size_t)(N_EDGES + 32) * 4);    // +32 pad
    __half* Wh        = (__half*)alloc((size_t)WH_ELEMS * 2);       // 80 KB
    __half* xh        = (__half*)alloc((size_t)N_NODES * D_IN * 2); // 12.8 MB
    __half* Sbuf      = (__half*)alloc(VSTRIDE * 2);                // 6.4 MB
    __half* u         = (__half*)alloc(5 * VSTRIDE * 2);            // u0..u4, 32 MB
    __half* b1        = (__half*)alloc(VSTRIDE * 2);
    __half* b3        = (__half*)alloc(VSTRIDE * 2);
    __half* b2        = (__half*)alloc(VSTRIDE * 2);
    __half* S  = Sbuf;

    // deg must start at 0 (workspace is poisoned)
    hipMemsetAsync(deg, 0, (size_t)DEG_PAD * 4, stream);

    // prep: xh fp16 convert + Wh build + pad-row clears + deg histogram
    prep_kernel<<<XH_BLOCKS + WH_BLOCKS + 1 + HIST_BLOCKS, 256, 0, stream>>>(
        x, cheb_w, erow, xh, Wh, u, b1, b3, b2, dinv, deg);

    // row_start = exclusive prefix(deg); cursor = copy
    scan_kernel<<<1, 1024, 0, stream>>>(deg, row_start, cursor);

    // fused: u_t = x @ W_t (persistent-weight MFMA) + edge scatter + dinv/dinv2/sdeg
    fused_kernel<<<VG_BLOCKS + SC_BLOCKS + DN_BLOCKS, 256, 0, stream>>>(
        erow, ecol, cursor, ewc, xh, Wh, u, deg, dinv, dinv2, sdeg);

    __half* u0 = u;
    __half* u1 = u + 1 * VSTRIDE;
    __half* u2 = u + 2 * VSTRIDE;
    __half* u3 = u + 3 * VSTRIDE;
    __half* u4 = u + 4 * VSTRIDE;
    const int PB = N_NODES / 8;   // 6250 blocks x 8 waves
    // b3 = dinv.*u3 + 2M(dinv.*u4)
    prop_kernel<1, 0, 0><<<PB, 512, 0, stream>>>(row_start, ewc, dinv2, dinv,
                                                 u4, u3, u3, 2.f, b3);
    // b2 = dinv.*u2 + 2M b3 - dinv.*u4
    prop_kernel<0, 1, 1><<<PB, 512, 0, stream>>>(row_start, ewc, dinv2, dinv,
                                                 b3, u2, u4, 2.f, b2);
    // b1 = dinv.*u1 + 2M b2 - b3
    prop_kernel<0, 1, 0><<<PB, 512, 0, stream>>>(row_start, ewc, dinv2, dinv,
                                                 b2, u1, b3, 2.f, b1);
    // S = dinv.*u0 + M b1 - b2
    prop_kernel<0, 1, 0><<<PB, 512, 0, stream>>>(row_start, ewc, dinv2, dinv,
                                                 b1, u0, b2, 1.f, S);

    // out = log_softmax(relu(sdeg*S + bias) @ fc_w + fc_b)
    final_kernel<<<(N_NODES + 255) / 256, 256, 0, stream>>>(S, sdeg, cheb_b,
                                                            fc_w, fc_b, out);
}

// Round 3
// 395.461 us; speedup vs baseline: 1.1461x; 1.1461x over previous
//
#include <hip/hip_runtime.h>
#include <hip/hip_fp16.h>

#define N_NODES 50000
#define N_EDGES 1600000
#define D_IN    128
#define D_HID   50
#define D_OUT   10
#define K_CHEB  5

#define WH_ELEMS  (K_CHEB * 64 * D_IN)    // 40960 halfs (W^T, n padded to 64)
#define WH_BLOCKS ((WH_ELEMS + 255) / 256)        // 160
#define XH_BLOCKS (N_NODES * D_IN / 8 / 256)      // 3125 (exact)

#define HIST_BLOCKS 1250                  // 1250 * 1280 = 1.6M exact
#define HIST_EPB    1280

#define DEG_PAD   50176                   // 256 * 196 (scan chunking)
#define SCAN_NPT  196                     // nodes per scan thread (49 uint4)

// bucket sort: bucket = row >> 8 (196 buckets of 256 rows), 512 block strips
#define P1S_BLOCKS 512
#define EPB        (N_EDGES / P1S_BLOCKS) // 3125 edges per strip
#define NBUCK      256                    // padded bucket count (196 used)
#define NB_USED    196
#define BCAP       48                     // per-(strip,bucket) cap; mean 16, +8 sd

#define DN_BLOCKS ((N_NODES + 255) / 256)             // 196

#define VROW      64                      // padded hidden row (halfs) = 128 B
#define VSTRIDE   ((size_t)(N_NODES + 1) * VROW)  // +1 zeroed pad row

#define NGROUP    (N_NODES / 16)          // 3125 node groups (exact)
#define VG_SPAN   512                     // waves per term
#define VG_WAVES  (K_CHEB * VG_SPAN)      // 2560 waves
#define VG_BLOCKS (VG_WAVES / 4)          // 640 blocks x 4 waves

typedef _Float16 half8_t __attribute__((ext_vector_type(8)));
typedef float    f32x4_t __attribute__((ext_vector_type(4)));

// R19: R18's atomic-cursor scatter regressed 3.4x (dependent atomicAdd chains on
// contended lines + 4B-in-64B write amplification: WRITE_SIZE 40->132 MB). Back
// to the bucketed strip sort, restructured:
//  - pass1 strips 256->512 blocks (2/CU: halves per-thread serial trips, 2x
//    latency hiding); strip regions 49 KB -> L2-resident writes.
//  - pass2 needs NO scans anymore: row_start comes from the deg histogram
//    (prep, fire-and-forget atomics - those were fast) + a scan block fused
//    into fused_kernel. pass2 = seed 256 LDS cursors, sweep strips (1 thread
//    per strip, L1-sequential reads), scatter into the bucket's contiguous
//    CSR window.
//  - props: gather chunk 32->16 edges (~16% less pad/tail gather waste,
//    E[16*ceil(d/16)]=39 vs E[32*ceil(d/32)]=47 per row).

// ---------------- prep: xh convert + Wh build + pad clears + deg histogram ----
__global__ __launch_bounds__(256) void prep_kernel(const float* __restrict__ x,
                                                   const float* __restrict__ W,
                                                   const int* __restrict__ row,
                                                   __half* __restrict__ xh,
                                                   __half* __restrict__ Wh,
                                                   __half* __restrict__ u,
                                                   __half* __restrict__ b1,
                                                   __half* __restrict__ b3,
                                                   __half* __restrict__ b2,
                                                   float* __restrict__ dinv,
                                                   int* __restrict__ deg) {
    int tid = threadIdx.x;
    int blk = blockIdx.x;
    if (blk < XH_BLOCKS) {                // x (fp32) -> xh (fp16), 8 elems/thread
        size_t base = ((size_t)blk * 256 + tid) * 8;
        float4 a = *(const float4*)(x + base);
        float4 b = *(const float4*)(x + base + 4);
        half8_t h;
        h[0] = (_Float16)a.x; h[1] = (_Float16)a.y;
        h[2] = (_Float16)a.z; h[3] = (_Float16)a.w;
        h[4] = (_Float16)b.x; h[5] = (_Float16)b.y;
        h[6] = (_Float16)b.z; h[7] = (_Float16)b.w;
        *(half8_t*)(xh + base) = h;
    } else if (blk < XH_BLOCKS + WH_BLOCKS) {  // Wh = fp16 W^T padded: [t][n<64][i<128]
        int idx = (blk - XH_BLOCKS) * 256 + tid;
        if (idx < WH_ELEMS) {
            int i = idx & 127;
            int n = (idx >> 7) & 63;
            int t = idx >> 13;
            float vv = (n < D_HID) ? W[t * D_IN * D_HID + i * D_HID + n] : 0.f;
            Wh[idx] = __float2half(vv);
        }
    } else if (blk == XH_BLOCKS + WH_BLOCKS) { // zero all gather-target pad rows
        if (tid < VROW) {
            __half z = __float2half(0.f);
            u[4 * VSTRIDE + (size_t)N_NODES * VROW + tid] = z;   // u4 pad
            b1[(size_t)N_NODES * VROW + tid] = z;
            b3[(size_t)N_NODES * VROW + tid] = z;
            b2[(size_t)N_NODES * VROW + tid] = z;
        }
        if (tid == 64) dinv[N_NODES] = 0.f;   // pad entry read by masked lanes
    } else {                              // degree histogram (deg pre-zeroed)
        int hb = blk - (XH_BLOCKS + WH_BLOCKS + 1);
        int base = hb * HIST_EPB;
        for (int i = tid; i < HIST_EPB; i += 256)
            atomicAdd(&deg[row[base + i]], 1);   // no return use: fire-and-forget
    }
}

// -------- fused: vgemm (0..639) + scan (640) + pass1 strips (641..1152) + dinv ----
__global__ __launch_bounds__(256) void fused_kernel(const int* __restrict__ row,
                                                    const int* __restrict__ col,
                                                    unsigned int* __restrict__ store,
                                                    int* __restrict__ bcnt,
                                                    const __half* __restrict__ xh,
                                                    const __half* __restrict__ Wh,
                                                    __half* __restrict__ u,
                                                    const int* __restrict__ deg,
                                                    int* __restrict__ row_start,
                                                    float* __restrict__ dinv,
                                                    float* __restrict__ dinv2,
                                                    float* __restrict__ sdeg) {
    __shared__ int cnt[NBUCK];
    int tid = threadIdx.x;
    int blk = blockIdx.x;
    if (blk < VG_BLOCKS) {
        int lane = tid & 63;
        int wv = __builtin_amdgcn_readfirstlane(tid >> 6);
        int w = blk * 4 + wv;             // 0..2559; 512%4==0 -> t uniform per block
        int t = w / VG_SPAN;              // 0..4
        int idx = w - t * VG_SPAN;        // 0..511
        int m = lane & 15;                // node within group (B n-index)
        int quad = lane >> 4;             // k-quad

        const __half* Wt = Wh + t * (64 * D_IN);
        half8_t afr[4][4];                // persistent A-frags (64 VGPRs)
        #pragma unroll
        for (int ks = 0; ks < 4; ++ks) {
            int ko = ks * 32 + quad * 8;
            #pragma unroll
            for (int jt = 0; jt < 4; ++jt)
                afr[ks][jt] = *(const half8_t*)(Wt + (jt * 16 + m) * D_IN + ko);
        }

        __half* ut = u + t * VSTRIDE;

        half8_t pf[4];
        int g = idx;
        {
            const __half* xr = xh + (size_t)(g * 16 + m) * D_IN;
            #pragma unroll
            for (int ks = 0; ks < 4; ++ks)
                pf[ks] = *(const half8_t*)(xr + ks * 32 + quad * 8);
        }

        for (; g < NGROUP; g += VG_SPAN) {
            int node = g * 16 + m;
            half8_t bfr[4];
            #pragma unroll
            for (int ks = 0; ks < 4; ++ks) bfr[ks] = pf[ks];
            int gn = g + VG_SPAN;
            if (gn < NGROUP) {            // prefetch next group's x while MFMAs run
                const __half* xr = xh + (size_t)(gn * 16 + m) * D_IN;
                #pragma unroll
                for (int ks = 0; ks < 4; ++ks)
                    pf[ks] = *(const half8_t*)(xr + ks * 32 + quad * 8);
            }
            f32x4_t acc[4];
            #pragma unroll
            for (int jt = 0; jt < 4; ++jt) acc[jt] = (f32x4_t)0.f;
            #pragma unroll
            for (int ks = 0; ks < 4; ++ks)
                #pragma unroll
                for (int jt = 0; jt < 4; ++jt)
                    acc[jt] = __builtin_amdgcn_mfma_f32_16x16x32_f16(afr[ks][jt], bfr[ks], acc[jt], 0, 0, 0);
            __half* dst = ut + (size_t)node * VROW + quad * 4;
            #pragma unroll
            for (int jt = 0; jt < 4; ++jt) {
                __half2 h0 = __float22half2_rn(make_float2(acc[jt][0], acc[jt][1]));
                __half2 h1 = __float22half2_rn(make_float2(acc[jt][2], acc[jt][3]));
                uint2 uu;
                uu.x = *(unsigned int*)&h0;
                uu.y = *(unsigned int*)&h1;
                *(uint2*)(dst + jt * 16) = uu;
            }
        }
        return;
    }
    if (blk == VG_BLOCKS) {               // ---- scan: row_start = excl prefix(deg) ----
        __shared__ int part[256];
        const uint4* d4 = (const uint4*)deg + (size_t)tid * (SCAN_NPT / 4);
        int sum = 0;
        #pragma unroll
        for (int i = 0; i < SCAN_NPT / 4; ++i) {
            uint4 v = d4[i];
            sum += (int)(v.x + v.y + v.z + v.w);
        }
        part[tid] = sum;
        __syncthreads();
        for (int o = 1; o < 256; o <<= 1) {
            int v = (tid >= o) ? part[tid - o] : 0;
            __syncthreads();
            part[tid] += v;
            __syncthreads();
        }
        int run = (tid == 0) ? 0 : part[tid - 1];
        int base = tid * SCAN_NPT;
        for (int i = 0; i < SCAN_NPT; ++i) {
            int n = base + i;
            if (n <= N_NODES) row_start[n] = run;
            run += deg[n];                // deg zero-padded past N_NODES
        }
        return;
    }
    if (blk < VG_BLOCKS + 1 + P1S_BLOCKS) {   // ---- pass1: strip bucket scatter ----
        int sblk = blk - VG_BLOCKS - 1;       // 0..511
        cnt[tid] = 0;
        __syncthreads();
        int base = sblk * EPB;
        size_t sb = (size_t)sblk * (NBUCK * BCAP);
        for (int i = tid; i < EPB; i += 256) {
            int r = row[base + i];
            int c = col[base + i];
            int b = r >> 8;
            int pos = atomicAdd(&cnt[b], 1);
            if (pos >= BCAP) pos = BCAP - 1;   // memory-safety clamp; P(hit) ~ 0
            store[sb + b * BCAP + pos] = ((unsigned int)(r & 255) << 16) | (unsigned int)c;
        }
        __syncthreads();
        bcnt[sblk * NBUCK + tid] = cnt[tid];
        return;
    }
    // ---- dinv/dinv2/sdeg from deg ----
    int node = (blk - VG_BLOCKS - 1 - P1S_BLOCKS) * 256 + tid;
    if (node < N_NODES) {
        int d = deg[node];
        float fd = (float)d;
        dinv[node]  = d ? rsqrtf(fd) : 0.f;
        dinv2[node] = d ? (1.f / fd) : 0.f;
        sdeg[node]  = d ? sqrtf(fd)  : 0.f;
    }
}

// -------- pass2: scatter strips -> CSR (one block per bucket, LDS cursors) ----
__global__ __launch_bounds__(512) void pass2_kernel(const unsigned int* __restrict__ store,
                                                    const int* __restrict__ bcnt,
                                                    const int* __restrict__ row_start,
                                                    int* __restrict__ ewc) {
    __shared__ int fill[256];
    __shared__ int rbase[256];
    int tid = threadIdx.x;
    int b = blockIdx.x;
    if (tid < 256) {
        fill[tid] = 0;
        int r = (b << 8) + tid;
        rbase[tid] = (r < N_NODES) ? row_start[r] : 0;
    }
    __syncthreads();
    int strip = tid;                     // 512 threads == 512 strips
    int sn = bcnt[strip * NBUCK + b];
    size_t sb = (size_t)strip * (NBUCK * BCAP) + b * BCAP;
    for (int i = 0; i < sn; ++i) {       // sequential 4B reads: L1-hot after line 1
        unsigned int v = store[sb + i];
        int rl = v >> 16;
        int c = v & 0xffff;
        int p = atomicAdd(&fill[rl], 1);
        ewc[rbase[rl] + p] = c;          // confined to bucket's 32 KB CSR window
    }
}

// ---------------- Clenshaw SpMM step in hidden space ----------------
// dst[r] = dinv[r]*addv[r] + (-alphaM*dinv2[r]) * sum_{c in N(r)} sc(c)*src[c]
//          - DO_SUB * (SCALE_SUB ? dinv[r] : 1) * subv[r]
// sc(c) = SCALE_SRC ? dinv[c] : 1. addv is always u-space (scaled by dinv[r]).
// 1 wave/row; 8 lanes x 16 B cover the 128 B row; 16-edge chunks (2x8 slots).
template<int SCALE_SRC, int DO_SUB, int SCALE_SUB>
__global__ __launch_bounds__(512) void prop_kernel(const int* __restrict__ row_start,
                                                   const int* __restrict__ ewc,
                                                   const float* __restrict__ dinv2,
                                                   const float* __restrict__ dinv,
                                                   const __half* __restrict__ src,
                                                   const __half* __restrict__ addv,
                                                   const __half* __restrict__ subv,
                                                   float alphaM,
                                                   __half* __restrict__ dst) {
    int tid = threadIdx.x;
    int lane = tid & 63;
    int wv = __builtin_amdgcn_readfirstlane(tid >> 6);  // 0..7
    int r = blockIdx.x * 8 + wv;                        // 6250*8 == 50000
    int e0 = row_start[r], e1 = row_start[r + 1];
    float fac = -alphaM * dinv2[r];
    int l = lane & 7;            // uint4 unit within row (8 x 16 B = 128 B)
    int g = lane >> 3;           // edge slot 0..7
    const uint4* src16 = (const uint4*)src;   // row stride 8 uint4
    float ac[8];
    #pragma unroll
    for (int j = 0; j < 8; ++j) ac[j] = 0.f;
    for (int e = e0; e < e1; e += 16) {
        #pragma unroll
        for (int i = 0; i < 2; ++i) {
            int base = e + 8 * i;
            int cl = ewc[base + g];              // per-lane load, 1 line / instr
            if (base + g >= e1) cl = N_NODES;    // zeroed pad row (dinv[N]=0 too)
            uint4 uu = src16[(size_t)cl * 8 + l];
            float2 f0 = __half22float2(*(__half2*)&uu.x);
            float2 f1 = __half22float2(*(__half2*)&uu.y);
            float2 f2 = __half22float2(*(__half2*)&uu.z);
            float2 f3 = __half22float2(*(__half2*)&uu.w);
            if (SCALE_SRC) {
                float dc = dinv[cl];             // broadcast within 8-lane group
                ac[0] = fmaf(dc, f0.x, ac[0]); ac[1] = fmaf(dc, f0.y, ac[1]);
                ac[2] = fmaf(dc, f1.x, ac[2]); ac[3] = fmaf(dc, f1.y, ac[3]);
                ac[4] = fmaf(dc, f2.x, ac[4]); ac[5] = fmaf(dc, f2.y, ac[5]);
                ac[6] = fmaf(dc, f3.x, ac[6]); ac[7] = fmaf(dc, f3.y, ac[7]);
            } else {
                ac[0] += f0.x; ac[1] += f0.y; ac[2] += f1.x; ac[3] += f1.y;
                ac[4] += f2.x; ac[5] += f2.y; ac[6] += f3.x; ac[7] += f3.y;
            }
        }
    }
    // reduce across the 8 edge slots (lane bits 3,4,5)
    #pragma unroll
    for (int k = 8; k <= 32; k <<= 1) {
        #pragma unroll
        for (int j = 0; j < 8; ++j) ac[j] += __shfl_xor(ac[j], k);
    }
    if (g == 0) {
        float sa = dinv[r];              // addv always u-space
        size_t o = (size_t)r * 8 + l;    // uint4 index
        uint4 av = ((const uint4*)addv)[o];
        float2 av0 = __half22float2(*(__half2*)&av.x);
        float2 av1 = __half22float2(*(__half2*)&av.y);
        float2 av2 = __half22float2(*(__half2*)&av.z);
        float2 av3 = __half22float2(*(__half2*)&av.w);
        float r0 = fmaf(sa, av0.x, fac * ac[0]);
        float r1 = fmaf(sa, av0.y, fac * ac[1]);
        float r2 = fmaf(sa, av1.x, fac * ac[2]);
        float r3 = fmaf(sa, av1.y, fac * ac[3]);
        float r4 = fmaf(sa, av2.x, fac * ac[4]);
        float r5 = fmaf(sa, av2.y, fac * ac[5]);
        float r6 = fmaf(sa, av3.x, fac * ac[6]);
        float r7 = fmaf(sa, av3.y, fac * ac[7]);
        if (DO_SUB) {
            float ss = SCALE_SUB ? dinv[r] : 1.f;
            uint4 sv = ((const uint4*)subv)[o];
            float2 sv0 = __half22float2(*(__half2*)&sv.x);
            float2 sv1 = __half22float2(*(__half2*)&sv.y);
            float2 sv2 = __half22float2(*(__half2*)&sv.z);
            float2 sv3 = __half22float2(*(__half2*)&sv.w);
            r0 = fmaf(-ss, sv0.x, r0); r1 = fmaf(-ss, sv0.y, r1);
            r2 = fmaf(-ss, sv1.x, r2); r3 = fmaf(-ss, sv1.y, r3);
            r4 = fmaf(-ss, sv2.x, r4); r5 = fmaf(-ss, sv2.y, r5);
            r6 = fmaf(-ss, sv3.x, r6); r7 = fmaf(-ss, sv3.y, r7);
        }
        __half2 h0 = __float22half2_rn(make_float2(r0, r1));
        __half2 h1 = __float22half2_rn(make_float2(r2, r3));
        __half2 h2 = __float22half2_rn(make_float2(r4, r5));
        __half2 h3 = __float22half2_rn(make_float2(r6, r7));
        uint4 uu;
        uu.x = *(unsigned int*)&h0;
        uu.y = *(unsigned int*)&h1;
        uu.z = *(unsigned int*)&h2;
        uu.w = *(unsigned int*)&h3;
        ((uint4*)dst)[o] = uu;
    }
}

// ---------------- epilogue: relu(sdeg*S + bias) -> FC -> log_softmax ----------------
__global__ __launch_bounds__(256) void final_kernel(const __half* __restrict__ S,
                                                    const float* __restrict__ sdeg,
                                                    const float* __restrict__ cheb_b,
                                                    const float* __restrict__ fc_w,
                                                    const float* __restrict__ fc_b,
                                                    float* __restrict__ out) {
    int r = blockIdx.x * blockDim.x + threadIdx.x;
    if (r >= N_NODES) return;
    float sc = sdeg[r];
    const __half2* s2 = (const __half2*)(S + (size_t)r * VROW);
    float h[D_HID];
    #pragma unroll
    for (int i = 0; i < D_HID / 2; ++i) {
        float2 f = __half22float2(s2[i]);
        float v0 = sc * f.x + cheb_b[2 * i];
        float v1 = sc * f.y + cheb_b[2 * i + 1];
        h[2 * i]     = v0 > 0.f ? v0 : 0.f;
        h[2 * i + 1] = v1 > 0.f ? v1 : 0.f;
    }
    float lg[D_OUT];
    #pragma unroll
    for (int o = 0; o < D_OUT; ++o) lg[o] = fc_b[o];
    #pragma unroll 2
    for (int i = 0; i < D_HID; ++i) {
        float hv = h[i];
        #pragma unroll
        for (int o = 0; o < D_OUT; ++o) lg[o] += hv * fc_w[i * D_OUT + o];
    }
    float mx = lg[0];
    #pragma unroll
    for (int o = 1; o < D_OUT; ++o) mx = fmaxf(mx, lg[o]);
    float s = 0.f;
    #pragma unroll
    for (int o = 0; o < D_OUT; ++o) s += __expf(lg[o] - mx);
    float ls = __logf(s);
    size_t oo = (size_t)r * D_OUT;
    #pragma unroll
    for (int o = 0; o < D_OUT; ++o) out[oo + o] = lg[o] - mx - ls;
}

extern "C" void kernel_launch(void* const* d_in, const int* in_sizes, int n_in,
                              void* d_out, int out_size, void* d_ws, size_t ws_size,
                              hipStream_t stream) {
    const float* x      = (const float*)d_in[0];
    const int*   edge   = (const int*)d_in[1];
    const float* cheb_w = (const float*)d_in[2];
    const float* cheb_b = (const float*)d_in[3];
    const float* fc_w   = (const float*)d_in[4];
    const float* fc_b   = (const float*)d_in[5];
    float* out = (float*)d_out;

    const int* erow = edge;
    const int* ecol = edge + N_EDGES;

    uintptr_t p = ((uintptr_t)d_ws + 255) & ~(uintptr_t)255;
    auto alloc = [&](size_t bytes) {
        uintptr_t q = p;
        p = (p + bytes + 255) & ~(uintptr_t)255;
        return (void*)q;
    };
    int*    deg       = (int*)alloc((size_t)DEG_PAD * 4);           // zeroed below
    int*    row_start = (int*)alloc((size_t)(N_NODES + 1) * 4);
    float*  dinv      = (float*)alloc((size_t)(N_NODES + 1) * 4);   // +1 pad (=0)
    float*  dinv2     = (float*)alloc((size_t)N_NODES * 4);
    float*  sdeg      = (float*)alloc((size_t)N_NODES * 4);
    int*    ewc       = (int*)alloc((size_t)(N_EDGES + 32) * 4);    // +32 pad
    unsigned int* store = (unsigned int*)alloc((size_t)P1S_BLOCKS * NBUCK * BCAP * 4); // 25.2 MB
    int*    bcnt      = (int*)alloc((size_t)P1S_BLOCKS * NBUCK * 4);  // 512 KB
    __half* Wh        = (__half*)alloc((size_t)WH_ELEMS * 2);       // 80 KB
    __half* xh        = (__half*)alloc((size_t)N_NODES * D_IN * 2); // 12.8 MB
    __half* Sbuf      = (__half*)alloc(VSTRIDE * 2);                // 6.4 MB
    __half* u         = (__half*)alloc(5 * VSTRIDE * 2);            // u0..u4, 32 MB
    __half* b1        = (__half*)alloc(VSTRIDE * 2);
    __half* b3        = (__half*)alloc(VSTRIDE * 2);
    __half* b2        = (__half*)alloc(VSTRIDE * 2);
    __half* S  = Sbuf;

    // deg must start at 0 (workspace is poisoned)
    hipMemsetAsync(deg, 0, (size_t)DEG_PAD * 4, stream);

    // prep: xh fp16 convert + Wh build + pad-row clears + deg histogram
    prep_kernel<<<XH_BLOCKS + WH_BLOCKS + 1 + HIST_BLOCKS, 256, 0, stream>>>(
        x, cheb_w, erow, xh, Wh, u, b1, b3, b2, dinv, deg);

    // fused: vgemm + scan(row_start) + pass1 strip scatter + dinv/dinv2/sdeg
    fused_kernel<<<VG_BLOCKS + 1 + P1S_BLOCKS + DN_BLOCKS, 256, 0, stream>>>(
        erow, ecol, store, bcnt, xh, Wh, u, deg, row_start, dinv, dinv2, sdeg);

    // pass2: strips -> CSR
    pass2_kernel<<<NB_USED, 512, 0, stream>>>(store, bcnt, row_start, ewc);

    __half* u0 = u;
    __half* u1 = u + 1 * VSTRIDE;
    __half* u2 = u + 2 * VSTRIDE;
    __half* u3 = u + 3 * VSTRIDE;
    __half* u4 = u + 4 * VSTRIDE;
    const int PB = N_NODES / 8;   // 6250 blocks x 8 waves
    // b3 = dinv.*u3 + 2M(dinv.*u4)
    prop_kernel<1, 0, 0><<<PB, 512, 0, stream>>>(row_start, ewc, dinv2, dinv,
                                                 u4, u3, u3, 2.f, b3);
    // b2 = dinv.*u2 + 2M b3 - dinv.*u4
    prop_kernel<0, 1, 1><<<PB, 512, 0, stream>>>(row_start, ewc, dinv2, dinv,
                                                 b3, u2, u4, 2.f, b2);
    // b1 = dinv.*u1 + 2M b2 - b3
    prop_kernel<0, 1, 0><<<PB, 512, 0, stream>>>(row_start, ewc, dinv2, dinv,
                                                 b2, u1, b3, 2.f, b1);
    // S = dinv.*u0 + M b1 - b2
    prop_kernel<0, 1, 0><<<PB, 512, 0, stream>>>(row_start, ewc, dinv2, dinv,
                                                 b1, u0, b2, 1.f, S);

    // out = log_softmax(relu(sdeg*S + bias) @ fc_w + fc_b)
    final_kernel<<<(N_NODES + 255) / 256, 256, 0, stream>>>(S, sdeg, cheb_b,
                                                            fc_w, fc_b, out);
}

// Round 4
// 371.651 us; speedup vs baseline: 1.2195x; 1.0641x over previous
//
#include <hip/hip_runtime.h>
#include <hip/hip_fp16.h>

#define N_NODES 50000
#define N_EDGES 1600000
#define D_IN    128
#define D_HID   50
#define D_OUT   10
#define K_CHEB  5

#define WH_ELEMS  (K_CHEB * 64 * D_IN)    // 40960 halfs (W^T, n padded to 64)
#define WH_BLOCKS ((WH_ELEMS + 255) / 256)        // 160
#define XH_BLOCKS (N_NODES * D_IN / 8 / 256)      // 3125 (exact)

#define HIST_BLOCKS 1250                  // 1250 * 1280 = 1.6M exact
#define HIST_EPB    1280

// scan geometry: 1024 threads x 52 nodes, register-staged
#define SCAN_TPB  1024
#define SCAN_NV   13                      // uint4 per thread
#define SCAN_NPT  (SCAN_NV * 4)           // 52 nodes per thread
#define DEG_PAD   (SCAN_TPB * SCAN_NPT)   // 53248 (>= N_NODES, zero-padded)

// bucket sort: bucket = row >> 8 (196 buckets of 256 rows), 512 block strips
#define P1S_BLOCKS 512
#define EPB        (N_EDGES / P1S_BLOCKS) // 3125 edges per strip
#define NBUCK      256                    // padded bucket count (196 used)
#define NB_USED    196
#define BCAP       48                     // per-(strip,bucket) cap; mean 16, +8 sd

#define VROW      64                      // padded hidden row (halfs) = 128 B
#define VSTRIDE   ((size_t)(N_NODES + 1) * VROW)  // +1 zeroed pad row

#define NGROUP    (N_NODES / 16)          // 3125 node groups (exact)
#define VG_SPAN   512                     // waves per term
#define VG_WAVES  (K_CHEB * VG_SPAN)      // 2560 waves
#define VG_BLOCKS (VG_WAVES / 4)          // 640 blocks x 4 waves

typedef _Float16 half8_t __attribute__((ext_vector_type(8)));
typedef float    f32x4_t __attribute__((ext_vector_type(4)));

// R20: R19's regression was the scan folded into fused_kernel as a serial
// scalar tail (196-iter dependent loop, uncoalesced loads -> ~60us solo tail;
// occupancy 38%->6.6%). Scan is now a standalone REGISTER-STAGED kernel:
// all 13 uint4 of deg loaded upfront (pipelined), LDS scan of 1024 partials,
// run-chain in registers, unrolled uint4/float4 stores. It also computes
// dinv/dinv2/sdeg from in-register deg (drops the 196 dinv tail blocks from
// fused). fused = vgemm + 512 strip blocks only. Everything else = R19.

// ---------------- prep: xh convert + Wh build + pad clears + deg histogram ----
__global__ __launch_bounds__(256) void prep_kernel(const float* __restrict__ x,
                                                   const float* __restrict__ W,
                                                   const int* __restrict__ row,
                                                   __half* __restrict__ xh,
                                                   __half* __restrict__ Wh,
                                                   __half* __restrict__ u,
                                                   __half* __restrict__ b1,
                                                   __half* __restrict__ b3,
                                                   __half* __restrict__ b2,
                                                   int* __restrict__ deg) {
    int tid = threadIdx.x;
    int blk = blockIdx.x;
    if (blk < XH_BLOCKS) {                // x (fp32) -> xh (fp16), 8 elems/thread
        size_t base = ((size_t)blk * 256 + tid) * 8;
        float4 a = *(const float4*)(x + base);
        float4 b = *(const float4*)(x + base + 4);
        half8_t h;
        h[0] = (_Float16)a.x; h[1] = (_Float16)a.y;
        h[2] = (_Float16)a.z; h[3] = (_Float16)a.w;
        h[4] = (_Float16)b.x; h[5] = (_Float16)b.y;
        h[6] = (_Float16)b.z; h[7] = (_Float16)b.w;
        *(half8_t*)(xh + base) = h;
    } else if (blk < XH_BLOCKS + WH_BLOCKS) {  // Wh = fp16 W^T padded: [t][n<64][i<128]
        int idx = (blk - XH_BLOCKS) * 256 + tid;
        if (idx < WH_ELEMS) {
            int i = idx & 127;
            int n = (idx >> 7) & 63;
            int t = idx >> 13;
            float vv = (n < D_HID) ? W[t * D_IN * D_HID + i * D_HID + n] : 0.f;
            Wh[idx] = __float2half(vv);
        }
    } else if (blk == XH_BLOCKS + WH_BLOCKS) { // zero all gather-target pad rows
        if (tid < VROW) {
            __half z = __float2half(0.f);
            u[4 * VSTRIDE + (size_t)N_NODES * VROW + tid] = z;   // u4 pad
            b1[(size_t)N_NODES * VROW + tid] = z;
            b3[(size_t)N_NODES * VROW + tid] = z;
            b2[(size_t)N_NODES * VROW + tid] = z;
        }
    } else {                              // degree histogram (deg pre-zeroed)
        int hb = blk - (XH_BLOCKS + WH_BLOCKS + 1);
        int base = hb * HIST_EPB;
        for (int i = tid; i < HIST_EPB; i += 256)
            atomicAdd(&deg[row[base + i]], 1);   // no return use: fire-and-forget
    }
}

// -------- scan: row_start = excl prefix(deg); dinv/dinv2/sdeg from deg --------
// Register-staged: 13 uint4 loads upfront (independent, pipelined), LDS scan
// of 1024 partials, run-chain in registers, unrolled vector stores. Arrays are
// DEG_PAD-sized; nodes >= N_NODES have deg 0 -> dinv etc. = 0 (pad semantics).
__global__ __launch_bounds__(1024) void scan_kernel(const int* __restrict__ deg,
                                                    int* __restrict__ row_start,
                                                    float* __restrict__ dinv,
                                                    float* __restrict__ dinv2,
                                                    float* __restrict__ sdeg) {
    __shared__ int part[SCAN_TPB];
    int tid = threadIdx.x;
    uint4 v[SCAN_NV];
    const uint4* d4 = (const uint4*)deg + (size_t)tid * SCAN_NV;
    #pragma unroll
    for (int i = 0; i < SCAN_NV; ++i) v[i] = d4[i];
    int sum = 0;
    #pragma unroll
    for (int i = 0; i < SCAN_NV; ++i)
        sum += (int)(v[i].x + v[i].y + v[i].z + v[i].w);
    part[tid] = sum;
    __syncthreads();
    for (int o = 1; o < SCAN_TPB; o <<= 1) {
        int t = (tid >= o) ? part[tid - o] : 0;
        __syncthreads();
        part[tid] += t;
        __syncthreads();
    }
    int run = (tid == 0) ? 0 : part[tid - 1];
    uint4*  rs4 = (uint4*)row_start + (size_t)tid * SCAN_NV;
    float4* di4 = (float4*)dinv     + (size_t)tid * SCAN_NV;
    float4* d24 = (float4*)dinv2    + (size_t)tid * SCAN_NV;
    float4* sd4 = (float4*)sdeg     + (size_t)tid * SCAN_NV;
    #pragma unroll
    for (int i = 0; i < SCAN_NV; ++i) {
        uint4 o4; float4 f1, f2, f3;
        int d;
        d = (int)v[i].x; o4.x = (unsigned)run; run += d;
        { float fd = (float)d; f1.x = d ? rsqrtf(fd) : 0.f; f2.x = d ? (1.f / fd) : 0.f; f3.x = d ? sqrtf(fd) : 0.f; }
        d = (int)v[i].y; o4.y = (unsigned)run; run += d;
        { float fd = (float)d; f1.y = d ? rsqrtf(fd) : 0.f; f2.y = d ? (1.f / fd) : 0.f; f3.y = d ? sqrtf(fd) : 0.f; }
        d = (int)v[i].z; o4.z = (unsigned)run; run += d;
        { float fd = (float)d; f1.z = d ? rsqrtf(fd) : 0.f; f2.z = d ? (1.f / fd) : 0.f; f3.z = d ? sqrtf(fd) : 0.f; }
        d = (int)v[i].w; o4.w = (unsigned)run; run += d;
        { float fd = (float)d; f1.w = d ? rsqrtf(fd) : 0.f; f2.w = d ? (1.f / fd) : 0.f; f3.w = d ? sqrtf(fd) : 0.f; }
        rs4[i] = o4; di4[i] = f1; d24[i] = f2; sd4[i] = f3;
    }
}

// -------- fused: vgemm (0..639) + pass1 strips (640..1151) --------
__global__ __launch_bounds__(256) void fused_kernel(const int* __restrict__ row,
                                                    const int* __restrict__ col,
                                                    unsigned int* __restrict__ store,
                                                    int* __restrict__ bcnt,
                                                    const __half* __restrict__ xh,
                                                    const __half* __restrict__ Wh,
                                                    __half* __restrict__ u) {
    __shared__ int cnt[NBUCK];
    int tid = threadIdx.x;
    int blk = blockIdx.x;
    if (blk < VG_BLOCKS) {
        int lane = tid & 63;
        int wv = __builtin_amdgcn_readfirstlane(tid >> 6);
        int w = blk * 4 + wv;             // 0..2559; 512%4==0 -> t uniform per block
        int t = w / VG_SPAN;              // 0..4
        int idx = w - t * VG_SPAN;        // 0..511
        int m = lane & 15;                // node within group (B n-index)
        int quad = lane >> 4;             // k-quad

        const __half* Wt = Wh + t * (64 * D_IN);
        half8_t afr[4][4];                // persistent A-frags (64 VGPRs)
        #pragma unroll
        for (int ks = 0; ks < 4; ++ks) {
            int ko = ks * 32 + quad * 8;
            #pragma unroll
            for (int jt = 0; jt < 4; ++jt)
                afr[ks][jt] = *(const half8_t*)(Wt + (jt * 16 + m) * D_IN + ko);
        }

        __half* ut = u + t * VSTRIDE;

        half8_t pf[4];
        int g = idx;
        {
            const __half* xr = xh + (size_t)(g * 16 + m) * D_IN;
            #pragma unroll
            for (int ks = 0; ks < 4; ++ks)
                pf[ks] = *(const half8_t*)(xr + ks * 32 + quad * 8);
        }

        for (; g < NGROUP; g += VG_SPAN) {
            int node = g * 16 + m;
            half8_t bfr[4];
            #pragma unroll
            for (int ks = 0; ks < 4; ++ks) bfr[ks] = pf[ks];
            int gn = g + VG_SPAN;
            if (gn < NGROUP) {            // prefetch next group's x while MFMAs run
                const __half* xr = xh + (size_t)(gn * 16 + m) * D_IN;
                #pragma unroll
                for (int ks = 0; ks < 4; ++ks)
                    pf[ks] = *(const half8_t*)(xr + ks * 32 + quad * 8);
            }
            f32x4_t acc[4];
            #pragma unroll
            for (int jt = 0; jt < 4; ++jt) acc[jt] = (f32x4_t)0.f;
            #pragma unroll
            for (int ks = 0; ks < 4; ++ks)
                #pragma unroll
                for (int jt = 0; jt < 4; ++jt)
                    acc[jt] = __builtin_amdgcn_mfma_f32_16x16x32_f16(afr[ks][jt], bfr[ks], acc[jt], 0, 0, 0);
            __half* dst = ut + (size_t)node * VROW + quad * 4;
            #pragma unroll
            for (int jt = 0; jt < 4; ++jt) {
                __half2 h0 = __float22half2_rn(make_float2(acc[jt][0], acc[jt][1]));
                __half2 h1 = __float22half2_rn(make_float2(acc[jt][2], acc[jt][3]));
                uint2 uu;
                uu.x = *(unsigned int*)&h0;
                uu.y = *(unsigned int*)&h1;
                *(uint2*)(dst + jt * 16) = uu;
            }
        }
        return;
    }
    // ---- pass1: strip bucket scatter ----
    int sblk = blk - VG_BLOCKS;           // 0..511
    cnt[tid] = 0;
    __syncthreads();
    int base = sblk * EPB;
    size_t sb = (size_t)sblk * (NBUCK * BCAP);
    for (int i = tid; i < EPB; i += 256) {
        int r = row[base + i];
        int c = col[base + i];
        int b = r >> 8;
        int pos = atomicAdd(&cnt[b], 1);
        if (pos >= BCAP) pos = BCAP - 1;   // memory-safety clamp; P(hit) ~ 0
        store[sb + b * BCAP + pos] = ((unsigned int)(r & 255) << 16) | (unsigned int)c;
    }
    __syncthreads();
    bcnt[sblk * NBUCK + tid] = cnt[tid];
}

// -------- pass2: scatter strips -> CSR (one block per bucket, LDS cursors) ----
__global__ __launch_bounds__(512) void pass2_kernel(const unsigned int* __restrict__ store,
                                                    const int* __restrict__ bcnt,
                                                    const int* __restrict__ row_start,
                                                    int* __restrict__ ewc) {
    __shared__ int fill[256];
    __shared__ int rbase[256];
    int tid = threadIdx.x;
    int b = blockIdx.x;
    if (tid < 256) {
        fill[tid] = 0;
        int r = (b << 8) + tid;
        rbase[tid] = (r < N_NODES) ? row_start[r] : 0;
    }
    __syncthreads();
    int strip = tid;                     // 512 threads == 512 strips
    int sn = bcnt[strip * NBUCK + b];
    size_t sb = (size_t)strip * (NBUCK * BCAP) + b * BCAP;
    for (int i = 0; i < sn; ++i) {       // sequential 4B reads: L1-hot after line 1
        unsigned int v = store[sb + i];
        int rl = v >> 16;
        int c = v & 0xffff;
        int p = atomicAdd(&fill[rl], 1);
        ewc[rbase[rl] + p] = c;          // confined to bucket's 32 KB CSR window
    }
}

// ---------------- Clenshaw SpMM step in hidden space ----------------
// dst[r] = dinv[r]*addv[r] + (-alphaM*dinv2[r]) * sum_{c in N(r)} sc(c)*src[c]
//          - DO_SUB * (SCALE_SUB ? dinv[r] : 1) * subv[r]
// sc(c) = SCALE_SRC ? dinv[c] : 1. addv is always u-space (scaled by dinv[r]).
// 1 wave/row; 8 lanes x 16 B cover the 128 B row; 16-edge chunks (2x8 slots).
template<int SCALE_SRC, int DO_SUB, int SCALE_SUB>
__global__ __launch_bounds__(512) void prop_kernel(const int* __restrict__ row_start,
                                                   const int* __restrict__ ewc,
                                                   const float* __restrict__ dinv2,
                                                   const float* __restrict__ dinv,
                                                   const __half* __restrict__ src,
                                                   const __half* __restrict__ addv,
                                                   const __half* __restrict__ subv,
                                                   float alphaM,
                                                   __half* __restrict__ dst) {
    int tid = threadIdx.x;
    int lane = tid & 63;
    int wv = __builtin_amdgcn_readfirstlane(tid >> 6);  // 0..7
    int r = blockIdx.x * 8 + wv;                        // 6250*8 == 50000
    int e0 = row_start[r], e1 = row_start[r + 1];
    float fac = -alphaM * dinv2[r];
    int l = lane & 7;            // uint4 unit within row (8 x 16 B = 128 B)
    int g = lane >> 3;           // edge slot 0..7
    const uint4* src16 = (const uint4*)src;   // row stride 8 uint4
    float ac[8];
    #pragma unroll
    for (int j = 0; j < 8; ++j) ac[j] = 0.f;
    for (int e = e0; e < e1; e += 16) {
        #pragma unroll
        for (int i = 0; i < 2; ++i) {
            int base = e + 8 * i;
            int cl = ewc[base + g];              // per-lane load, 1 line / instr
            if (base + g >= e1) cl = N_NODES;    // zeroed pad row (dinv[N]=0 too)
            uint4 uu = src16[(size_t)cl * 8 + l];
            float2 f0 = __half22float2(*(__half2*)&uu.x);
            float2 f1 = __half22float2(*(__half2*)&uu.y);
            float2 f2 = __half22float2(*(__half2*)&uu.z);
            float2 f3 = __half22float2(*(__half2*)&uu.w);
            if (SCALE_SRC) {
                float dc = dinv[cl];             // broadcast within 8-lane group
                ac[0] = fmaf(dc, f0.x, ac[0]); ac[1] = fmaf(dc, f0.y, ac[1]);
                ac[2] = fmaf(dc, f1.x, ac[2]); ac[3] = fmaf(dc, f1.y, ac[3]);
                ac[4] = fmaf(dc, f2.x, ac[4]); ac[5] = fmaf(dc, f2.y, ac[5]);
                ac[6] = fmaf(dc, f3.x, ac[6]); ac[7] = fmaf(dc, f3.y, ac[7]);
            } else {
                ac[0] += f0.x; ac[1] += f0.y; ac[2] += f1.x; ac[3] += f1.y;
                ac[4] += f2.x; ac[5] += f2.y; ac[6] += f3.x; ac[7] += f3.y;
            }
        }
    }
    // reduce across the 8 edge slots (lane bits 3,4,5)
    #pragma unroll
    for (int k = 8; k <= 32; k <<= 1) {
        #pragma unroll
        for (int j = 0; j < 8; ++j) ac[j] += __shfl_xor(ac[j], k);
    }
    if (g == 0) {
        float sa = dinv[r];              // addv always u-space
        size_t o = (size_t)r * 8 + l;    // uint4 index
        uint4 av = ((const uint4*)addv)[o];
        float2 av0 = __half22float2(*(__half2*)&av.x);
        float2 av1 = __half22float2(*(__half2*)&av.y);
        float2 av2 = __half22float2(*(__half2*)&av.z);
        float2 av3 = __half22float2(*(__half2*)&av.w);
        float r0 = fmaf(sa, av0.x, fac * ac[0]);
        float r1 = fmaf(sa, av0.y, fac * ac[1]);
        float r2 = fmaf(sa, av1.x, fac * ac[2]);
        float r3 = fmaf(sa, av1.y, fac * ac[3]);
        float r4 = fmaf(sa, av2.x, fac * ac[4]);
        float r5 = fmaf(sa, av2.y, fac * ac[5]);
        float r6 = fmaf(sa, av3.x, fac * ac[6]);
        float r7 = fmaf(sa, av3.y, fac * ac[7]);
        if (DO_SUB) {
            float ss = SCALE_SUB ? dinv[r] : 1.f;
            uint4 sv = ((const uint4*)subv)[o];
            float2 sv0 = __half22float2(*(__half2*)&sv.x);
            float2 sv1 = __half22float2(*(__half2*)&sv.y);
            float2 sv2 = __half22float2(*(__half2*)&sv.z);
            float2 sv3 = __half22float2(*(__half2*)&sv.w);
            r0 = fmaf(-ss, sv0.x, r0); r1 = fmaf(-ss, sv0.y, r1);
            r2 = fmaf(-ss, sv1.x, r2); r3 = fmaf(-ss, sv1.y, r3);
            r4 = fmaf(-ss, sv2.x, r4); r5 = fmaf(-ss, sv2.y, r5);
            r6 = fmaf(-ss, sv3.x, r6); r7 = fmaf(-ss, sv3.y, r7);
        }
        __half2 h0 = __float22half2_rn(make_float2(r0, r1));
        __half2 h1 = __float22half2_rn(make_float2(r2, r3));
        __half2 h2 = __float22half2_rn(make_float2(r4, r5));
        __half2 h3 = __float22half2_rn(make_float2(r6, r7));
        uint4 uu;
        uu.x = *(unsigned int*)&h0;
        uu.y = *(unsigned int*)&h1;
        uu.z = *(unsigned int*)&h2;
        uu.w = *(unsigned int*)&h3;
        ((uint4*)dst)[o] = uu;
    }
}

// ---------------- epilogue: relu(sdeg*S + bias) -> FC -> log_softmax ----------------
__global__ __launch_bounds__(256) void final_kernel(const __half* __restrict__ S,
                                                    const float* __restrict__ sdeg,
                                                    const float* __restrict__ cheb_b,
                                                    const float* __restrict__ fc_w,
                                                    const float* __restrict__ fc_b,
                                                    float* __restrict__ out) {
    int r = blockIdx.x * blockDim.x + threadIdx.x;
    if (r >= N_NODES) return;
    float sc = sdeg[r];
    const __half2* s2 = (const __half2*)(S + (size_t)r * VROW);
    float h[D_HID];
    #pragma unroll
    for (int i = 0; i < D_HID / 2; ++i) {
        float2 f = __half22float2(s2[i]);
        float v0 = sc * f.x + cheb_b[2 * i];
        float v1 = sc * f.y + cheb_b[2 * i + 1];
        h[2 * i]     = v0 > 0.f ? v0 : 0.f;
        h[2 * i + 1] = v1 > 0.f ? v1 : 0.f;
    }
    float lg[D_OUT];
    #pragma unroll
    for (int o = 0; o < D_OUT; ++o) lg[o] = fc_b[o];
    #pragma unroll 2
    for (int i = 0; i < D_HID; ++i) {
        float hv = h[i];
        #pragma unroll
        for (int o = 0; o < D_OUT; ++o) lg[o] += hv * fc_w[i * D_OUT + o];
    }
    float mx = lg[0];
    #pragma unroll
    for (int o = 1; o < D_OUT; ++o) mx = fmaxf(mx, lg[o]);
    float s = 0.f;
    #pragma unroll
    for (int o = 0; o < D_OUT; ++o) s += __expf(lg[o] - mx);
    float ls = __logf(s);
    size_t oo = (size_t)r * D_OUT;
    #pragma unroll
    for (int o = 0; o < D_OUT; ++o) out[oo + o] = lg[o] - mx - ls;
}

extern "C" void kernel_launch(void* const* d_in, const int* in_sizes, int n_in,
                              void* d_out, int out_size, void* d_ws, size_t ws_size,
                              hipStream_t stream) {
    const float* x      = (const float*)d_in[0];
    const int*   edge   = (const int*)d_in[1];
    const float* cheb_w = (const float*)d_in[2];
    const float* cheb_b = (const float*)d_in[3];
    const float* fc_w   = (const float*)d_in[4];
    const float* fc_b   = (const float*)d_in[5];
    float* out = (float*)d_out;

    const int* erow = edge;
    const int* ecol = edge + N_EDGES;

    uintptr_t p = ((uintptr_t)d_ws + 255) & ~(uintptr_t)255;
    auto alloc = [&](size_t bytes) {
        uintptr_t q = p;
        p = (p + bytes + 255) & ~(uintptr_t)255;
        return (void*)q;
    };
    int*    deg       = (int*)alloc((size_t)DEG_PAD * 4);           // zeroed below
    int*    row_start = (int*)alloc((size_t)DEG_PAD * 4);           // scan-padded
    float*  dinv      = (float*)alloc((size_t)DEG_PAD * 4);         // pad entries = 0
    float*  dinv2     = (float*)alloc((size_t)DEG_PAD * 4);
    float*  sdeg      = (float*)alloc((size_t)DEG_PAD * 4);
    int*    ewc       = (int*)alloc((size_t)(N_EDGES + 32) * 4);    // +32 pad
    unsigned int* store = (unsigned int*)alloc((size_t)P1S_BLOCKS * NBUCK * BCAP * 4); // 25.2 MB
    int*    bcnt      = (int*)alloc((size_t)P1S_BLOCKS * NBUCK * 4);  // 512 KB
    __half* Wh        = (__half*)alloc((size_t)WH_ELEMS * 2);       // 80 KB
    __half* xh        = (__half*)alloc((size_t)N_NODES * D_IN * 2); // 12.8 MB
    __half* Sbuf      = (__half*)alloc(VSTRIDE * 2);                // 6.4 MB
    __half* u         = (__half*)alloc(5 * VSTRIDE * 2);            // u0..u4, 32 MB
    __half* b1        = (__half*)alloc(VSTRIDE * 2);
    __half* b3        = (__half*)alloc(VSTRIDE * 2);
    __half* b2        = (__half*)alloc(VSTRIDE * 2);
    __half* S  = Sbuf;

    // deg must start at 0 (workspace is poisoned)
    hipMemsetAsync(deg, 0, (size_t)DEG_PAD * 4, stream);

    // prep: xh fp16 convert + Wh build + pad-row clears + deg histogram
    prep_kernel<<<XH_BLOCKS + WH_BLOCKS + 1 + HIST_BLOCKS, 256, 0, stream>>>(
        x, cheb_w, erow, xh, Wh, u, b1, b3, b2, deg);

    // scan: row_start prefix + dinv/dinv2/sdeg (register-staged, 1 block)
    scan_kernel<<<1, SCAN_TPB, 0, stream>>>(deg, row_start, dinv, dinv2, sdeg);

    // fused: vgemm + pass1 strip scatter
    fused_kernel<<<VG_BLOCKS + P1S_BLOCKS, 256, 0, stream>>>(
        erow, ecol, store, bcnt, xh, Wh, u);

    // pass2: strips -> CSR
    pass2_kernel<<<NB_USED, 512, 0, stream>>>(store, bcnt, row_start, ewc);

    __half* u0 = u;
    __half* u1 = u + 1 * VSTRIDE;
    __half* u2 = u + 2 * VSTRIDE;
    __half* u3 = u + 3 * VSTRIDE;
    __half* u4 = u + 4 * VSTRIDE;
    const int PB = N_NODES / 8;   // 6250 blocks x 8 waves
    // b3 = dinv.*u3 + 2M(dinv.*u4)
    prop_kernel<1, 0, 0><<<PB, 512, 0, stream>>>(row_start, ewc, dinv2, dinv,
                                                 u4, u3, u3, 2.f, b3);
    // b2 = dinv.*u2 + 2M b3 - dinv.*u4
    prop_kernel<0, 1, 1><<<PB, 512, 0, stream>>>(row_start, ewc, dinv2, dinv,
                                                 b3, u2, u4, 2.f, b2);
    // b1 = dinv.*u1 + 2M b2 - b3
    prop_kernel<0, 1, 0><<<PB, 512, 0, stream>>>(row_start, ewc, dinv2, dinv,
                                                 b2, u1, b3, 2.f, b1);
    // S = dinv.*u0 + M b1 - b2
    prop_kernel<0, 1, 0><<<PB, 512, 0, stream>>>(row_start, ewc, dinv2, dinv,
                                                 b1, u0, b2, 1.f, S);

    // out = log_softmax(relu(sdeg*S + bias) @ fc_w + fc_b)
    final_kernel<<<(N_NODES + 255) / 256, 256, 0, stream>>>(S, sdeg, cheb_b,
                                                            fc_w, fc_b, out);
}

// Round 5
// 295.006 us; speedup vs baseline: 1.5363x; 1.2598x over previous
//
#include <hip/hip_runtime.h>
#include <hip/hip_fp16.h>

#define N_NODES 50000
#define N_EDGES 1600000
#define D_IN    128
#define D_HID   50
#define D_OUT   10
#define K_CHEB  5

#define WH_ELEMS  (K_CHEB * 64 * D_IN)    // 40960 halfs (W^T, n padded to 64)
#define WH_BLOCKS ((WH_ELEMS + 255) / 256)        // 160
#define XH_BLOCKS (N_NODES * D_IN / 8 / 256)      // 3125 (exact)

// bucket sort: bucket = row >> 8 (196 buckets of 256 rows), 512 block strips
#define P1S_BLOCKS 512
#define EPB        (N_EDGES / P1S_BLOCKS) // 3125 edges per strip
#define NBUCK      256                    // padded bucket count (196 used)
#define NB_USED    196
#define BCAP       48                     // per-(strip,bucket) cap; mean 16, +8 sd

#define VROW      64                      // padded hidden row (halfs) = 128 B
#define VSTRIDE   ((size_t)(N_NODES + 1) * VROW)  // +1 zeroed pad row

#define NGROUP    (N_NODES / 16)          // 3125 node groups (exact)
#define VG_SPAN   512                     // waves per term
#define VG_WAVES  (K_CHEB * VG_SPAN)      // 2560 waves
#define VGB_BLOCKS (VG_WAVES / 8)         // 320 blocks x 8 waves (kernel B)

typedef _Float16 half8_t __attribute__((ext_vector_type(8)));
typedef float    f32x4_t __attribute__((ext_vector_type(4)));

// R21: revert to R17's PROVEN CSR build (strip sort + per-bucket LDS-cursor
// pass2; R18-R20's histogram/scan variants all regressed: global atomics
// cost 50 MB coherence traffic / 60 us, serial scan tails 60 us). The fix is
// CO-SCHEDULING, not a new algorithm:
//   kernel A = pass1 strips (512 blocks, FIRST in grid, latency-bound ~40us)
//              + prep xh/Wh/pads (BW work ~10us) -> overlap, ~max not sum.
//   kernel B = pass2 (196 bucket blocks, FIRST) + vgemm (320 blocks x 8
//              waves) -> vgemm hides under pass2 on the idle 60 CUs.
// Props keep R20's 16-edge chunks. 7 dispatches, no memsets.

// ---- kernel A: pass1 strips (0..511) + xh (512..3636) + Wh + pads ----
__global__ __launch_bounds__(256) void buildA_kernel(const int* __restrict__ row,
                                                     const int* __restrict__ col,
                                                     unsigned int* __restrict__ store,
                                                     int* __restrict__ bcnt,
                                                     const float* __restrict__ x,
                                                     const float* __restrict__ W,
                                                     __half* __restrict__ xh,
                                                     __half* __restrict__ Wh,
                                                     __half* __restrict__ u,
                                                     __half* __restrict__ b1,
                                                     __half* __restrict__ b3,
                                                     __half* __restrict__ b2,
                                                     float* __restrict__ dinv) {
    __shared__ int cnt[NBUCK];
    int tid = threadIdx.x;
    int blk = blockIdx.x;
    if (blk < P1S_BLOCKS) {               // ---- pass1: strip bucket scatter ----
        cnt[tid] = 0;
        __syncthreads();
        int base = blk * EPB;
        size_t sb = (size_t)blk * (NBUCK * BCAP);
        for (int i = tid; i < EPB; i += 256) {
            int r = row[base + i];
            int c = col[base + i];
            int b = r >> 8;
            int pos = atomicAdd(&cnt[b], 1);
            if (pos >= BCAP) pos = BCAP - 1;   // memory-safety clamp; P(hit) ~ 0
            store[sb + b * BCAP + pos] = ((unsigned int)(r & 255) << 16) | (unsigned int)c;
        }
        __syncthreads();
        bcnt[blk * NBUCK + tid] = cnt[tid];
        return;
    }
    int pb = blk - P1S_BLOCKS;
    if (pb < XH_BLOCKS) {                 // x (fp32) -> xh (fp16), 8 elems/thread
        size_t base = ((size_t)pb * 256 + tid) * 8;
        float4 a = *(const float4*)(x + base);
        float4 b = *(const float4*)(x + base + 4);
        half8_t h;
        h[0] = (_Float16)a.x; h[1] = (_Float16)a.y;
        h[2] = (_Float16)a.z; h[3] = (_Float16)a.w;
        h[4] = (_Float16)b.x; h[5] = (_Float16)b.y;
        h[6] = (_Float16)b.z; h[7] = (_Float16)b.w;
        *(half8_t*)(xh + base) = h;
    } else if (pb < XH_BLOCKS + WH_BLOCKS) {   // Wh = fp16 W^T padded: [t][n<64][i<128]
        int idx = (pb - XH_BLOCKS) * 256 + tid;
        if (idx < WH_ELEMS) {
            int i = idx & 127;
            int n = (idx >> 7) & 63;
            int t = idx >> 13;
            float vv = (n < D_HID) ? W[t * D_IN * D_HID + i * D_HID + n] : 0.f;
            Wh[idx] = __float2half(vv);
        }
    } else {                              // zero all gather-target pad rows
        if (tid < VROW) {
            __half z = __float2half(0.f);
            u[4 * VSTRIDE + (size_t)N_NODES * VROW + tid] = z;   // u4 pad
            b1[(size_t)N_NODES * VROW + tid] = z;
            b3[(size_t)N_NODES * VROW + tid] = z;
            b2[(size_t)N_NODES * VROW + tid] = z;
        }
        if (tid == 64) dinv[N_NODES] = 0.f;   // pad entry read by masked lanes
    }
}

// ---- kernel B: pass2 CSR build (blocks 0..195) + vgemm (196..515) ----
// pass2 (R17-proven, 512 strips): phase0 redundant bucket prefix, phase A
// per-strip degree histogram, phase B row prefix + dinv writes, phase C
// scatter into the bucket's contiguous CSR window.
// vgemm: 8 waves/block; wave w holds term t=w/512's 16 A-frags persistent in
// registers and grid-strides node groups (prefetch x while MFMAs run).
__global__ __launch_bounds__(512) void buildB_kernel(const unsigned int* __restrict__ store,
                                                     const int* __restrict__ bcnt,
                                                     int* __restrict__ row_start,
                                                     float* __restrict__ dinv,
                                                     float* __restrict__ dinv2,
                                                     float* __restrict__ sdeg,
                                                     int* __restrict__ ewc,
                                                     const __half* __restrict__ xh,
                                                     const __half* __restrict__ Wh,
                                                     __half* __restrict__ u) {
    __shared__ int hist[256];
    __shared__ int off[256];
    __shared__ int fill[256];
    __shared__ int sb_part[512];
    __shared__ int pscan[256];
    __shared__ int s_bbase;
    int tid = threadIdx.x;
    int blk = blockIdx.x;
    if (blk >= NB_USED) {                 // ---------------- vgemm ----------------
        int lane = tid & 63;
        int wv = __builtin_amdgcn_readfirstlane(tid >> 6);  // 0..7
        int w = (blk - NB_USED) * 8 + wv; // 0..2559; 512%8==0 -> t uniform per block
        int t = w / VG_SPAN;              // 0..4
        int idx = w - t * VG_SPAN;        // 0..511
        int m = lane & 15;                // node within group (B n-index)
        int quad = lane >> 4;             // k-quad

        const __half* Wt = Wh + t * (64 * D_IN);
        half8_t afr[4][4];                // persistent A-frags (64 VGPRs)
        #pragma unroll
        for (int ks = 0; ks < 4; ++ks) {
            int ko = ks * 32 + quad * 8;
            #pragma unroll
            for (int jt = 0; jt < 4; ++jt)
                afr[ks][jt] = *(const half8_t*)(Wt + (jt * 16 + m) * D_IN + ko);
        }

        __half* ut = u + t * VSTRIDE;

        half8_t pf[4];
        int g = idx;
        {
            const __half* xr = xh + (size_t)(g * 16 + m) * D_IN;
            #pragma unroll
            for (int ks = 0; ks < 4; ++ks)
                pf[ks] = *(const half8_t*)(xr + ks * 32 + quad * 8);
        }

        for (; g < NGROUP; g += VG_SPAN) {
            int node = g * 16 + m;
            half8_t bfr[4];
            #pragma unroll
            for (int ks = 0; ks < 4; ++ks) bfr[ks] = pf[ks];
            int gn = g + VG_SPAN;
            if (gn < NGROUP) {            // prefetch next group's x while MFMAs run
                const __half* xr = xh + (size_t)(gn * 16 + m) * D_IN;
                #pragma unroll
                for (int ks = 0; ks < 4; ++ks)
                    pf[ks] = *(const half8_t*)(xr + ks * 32 + quad * 8);
            }
            f32x4_t acc[4];
            #pragma unroll
            for (int jt = 0; jt < 4; ++jt) acc[jt] = (f32x4_t)0.f;
            #pragma unroll
            for (int ks = 0; ks < 4; ++ks)
                #pragma unroll
                for (int jt = 0; jt < 4; ++jt)
                    acc[jt] = __builtin_amdgcn_mfma_f32_16x16x32_f16(afr[ks][jt], bfr[ks], acc[jt], 0, 0, 0);
            __half* dst = ut + (size_t)node * VROW + quad * 4;
            #pragma unroll
            for (int jt = 0; jt < 4; ++jt) {
                __half2 h0 = __float22half2_rn(make_float2(acc[jt][0], acc[jt][1]));
                __half2 h1 = __float22half2_rn(make_float2(acc[jt][2], acc[jt][3]));
                uint2 uu;
                uu.x = *(unsigned int*)&h0;
                uu.y = *(unsigned int*)&h1;
                *(uint2*)(dst + jt * 16) = uu;
            }
        }
        return;
    }
    // ---------------- pass2 ----------------
    int b = blk;
    // phase 0: bucket totals + exclusive prefix (redundant per block)
    {
        int bt = tid & 255, seg = tid >> 8;       // 2 segs x 256 strips
        int sum = 0;
        for (int s = seg * 256; s < seg * 256 + 256; ++s) sum += bcnt[s * NBUCK + bt];
        sb_part[tid] = sum;
    }
    __syncthreads();
    if (tid < 256) pscan[tid] = sb_part[tid] + sb_part[256 + tid];
    __syncthreads();
    for (int o = 1; o < 256; o <<= 1) {
        int vv = (tid < 256 && tid >= o) ? pscan[tid - o] : 0;
        __syncthreads();
        if (tid < 256) pscan[tid] += vv;
        __syncthreads();
    }
    if (tid == 0) {
        s_bbase = (b == 0) ? 0 : pscan[b - 1];
        if (b == 0) row_start[N_NODES] = pscan[255];
    }
    if (tid < 256) hist[tid] = 0;
    __syncthreads();
    int bbase_b = s_bbase;

    int strip = tid;                      // 512 threads == 512 strips
    int sn = bcnt[strip * NBUCK + b];
    size_t sb = (size_t)strip * (NBUCK * BCAP) + b * BCAP;
    // phase A: degree histogram — one thread sweeps each strip
    for (int i = 0; i < sn; ++i)
        atomicAdd(&hist[store[sb + i] >> 16], 1);
    __syncthreads();
    int d = (tid < 256) ? hist[tid] : 0;
    if (tid < 256) off[tid] = d;
    __syncthreads();
    for (int o = 1; o < 256; o <<= 1) {
        int vv = (tid < 256 && tid >= o) ? off[tid - o] : 0;
        __syncthreads();
        if (tid < 256) off[tid] += vv;
        __syncthreads();
    }
    if (tid < 256) {
        int excl = off[tid] - d + bbase_b;
        hist[tid] = excl;        // reuse as per-row global base
        fill[tid] = 0;
        int r = (b << 8) + tid;
        if (r < N_NODES) {
            row_start[r] = excl;
            float fd = (float)d;
            dinv[r]  = d ? rsqrtf(fd)  : 0.f;
            dinv2[r] = d ? (1.f / fd)  : 0.f;
            sdeg[r]  = d ? sqrtf(fd)   : 0.f;
        }
    }
    __syncthreads();
    // phase C: scatter cols into final CSR (confined to bucket's CSR window)
    for (int i = 0; i < sn; ++i) {
        unsigned int vv = store[sb + i];
        int rl = vv >> 16;
        int c = vv & 0xffff;
        int p = atomicAdd(&fill[rl], 1);
        ewc[hist[rl] + p] = c;
    }
}

// ---------------- Clenshaw SpMM step in hidden space ----------------
// dst[r] = dinv[r]*addv[r] + (-alphaM*dinv2[r]) * sum_{c in N(r)} sc(c)*src[c]
//          - DO_SUB * (SCALE_SUB ? dinv[r] : 1) * subv[r]
// sc(c) = SCALE_SRC ? dinv[c] : 1. addv is always u-space (scaled by dinv[r]).
// 1 wave/row; 8 lanes x 16 B cover the 128 B row; 16-edge chunks (2x8 slots).
template<int SCALE_SRC, int DO_SUB, int SCALE_SUB>
__global__ __launch_bounds__(512) void prop_kernel(const int* __restrict__ row_start,
                                                   const int* __restrict__ ewc,
                                                   const float* __restrict__ dinv2,
                                                   const float* __restrict__ dinv,
                                                   const __half* __restrict__ src,
                                                   const __half* __restrict__ addv,
                                                   const __half* __restrict__ subv,
                                                   float alphaM,
                                                   __half* __restrict__ dst) {
    int tid = threadIdx.x;
    int lane = tid & 63;
    int wv = __builtin_amdgcn_readfirstlane(tid >> 6);  // 0..7
    int r = blockIdx.x * 8 + wv;                        // 6250*8 == 50000
    int e0 = row_start[r], e1 = row_start[r + 1];
    float fac = -alphaM * dinv2[r];
    int l = lane & 7;            // uint4 unit within row (8 x 16 B = 128 B)
    int g = lane >> 3;           // edge slot 0..7
    const uint4* src16 = (const uint4*)src;   // row stride 8 uint4
    float ac[8];
    #pragma unroll
    for (int j = 0; j < 8; ++j) ac[j] = 0.f;
    for (int e = e0; e < e1; e += 16) {
        #pragma unroll
        for (int i = 0; i < 2; ++i) {
            int base = e + 8 * i;
            int cl = ewc[base + g];              // per-lane load, 1 line / instr
            if (base + g >= e1) cl = N_NODES;    // zeroed pad row (dinv[N]=0 too)
            uint4 uu = src16[(size_t)cl * 8 + l];
            float2 f0 = __half22float2(*(__half2*)&uu.x);
            float2 f1 = __half22float2(*(__half2*)&uu.y);
            float2 f2 = __half22float2(*(__half2*)&uu.z);
            float2 f3 = __half22float2(*(__half2*)&uu.w);
            if (SCALE_SRC) {
                float dc = dinv[cl];             // broadcast within 8-lane group
                ac[0] = fmaf(dc, f0.x, ac[0]); ac[1] = fmaf(dc, f0.y, ac[1]);
                ac[2] = fmaf(dc, f1.x, ac[2]); ac[3] = fmaf(dc, f1.y, ac[3]);
                ac[4] = fmaf(dc, f2.x, ac[4]); ac[5] = fmaf(dc, f2.y, ac[5]);
                ac[6] = fmaf(dc, f3.x, ac[6]); ac[7] = fmaf(dc, f3.y, ac[7]);
            } else {
                ac[0] += f0.x; ac[1] += f0.y; ac[2] += f1.x; ac[3] += f1.y;
                ac[4] += f2.x; ac[5] += f2.y; ac[6] += f3.x; ac[7] += f3.y;
            }
        }
    }
    // reduce across the 8 edge slots (lane bits 3,4,5)
    #pragma unroll
    for (int k = 8; k <= 32; k <<= 1) {
        #pragma unroll
        for (int j = 0; j < 8; ++j) ac[j] += __shfl_xor(ac[j], k);
    }
    if (g == 0) {
        float sa = dinv[r];              // addv always u-space
        size_t o = (size_t)r * 8 + l;    // uint4 index
        uint4 av = ((const uint4*)addv)[o];
        float2 av0 = __half22float2(*(__half2*)&av.x);
        float2 av1 = __half22float2(*(__half2*)&av.y);
        float2 av2 = __half22float2(*(__half2*)&av.z);
        float2 av3 = __half22float2(*(__half2*)&av.w);
        float r0 = fmaf(sa, av0.x, fac * ac[0]);
        float r1 = fmaf(sa, av0.y, fac * ac[1]);
        float r2 = fmaf(sa, av1.x, fac * ac[2]);
        float r3 = fmaf(sa, av1.y, fac * ac[3]);
        float r4 = fmaf(sa, av2.x, fac * ac[4]);
        float r5 = fmaf(sa, av2.y, fac * ac[5]);
        float r6 = fmaf(sa, av3.x, fac * ac[6]);
        float r7 = fmaf(sa, av3.y, fac * ac[7]);
        if (DO_SUB) {
            float ss = SCALE_SUB ? dinv[r] : 1.f;
            uint4 sv = ((const uint4*)subv)[o];
            float2 sv0 = __half22float2(*(__half2*)&sv.x);
            float2 sv1 = __half22float2(*(__half2*)&sv.y);
            float2 sv2 = __half22float2(*(__half2*)&sv.z);
            float2 sv3 = __half22float2(*(__half2*)&sv.w);
            r0 = fmaf(-ss, sv0.x, r0); r1 = fmaf(-ss, sv0.y, r1);
            r2 = fmaf(-ss, sv1.x, r2); r3 = fmaf(-ss, sv1.y, r3);
            r4 = fmaf(-ss, sv2.x, r4); r5 = fmaf(-ss, sv2.y, r5);
            r6 = fmaf(-ss, sv3.x, r6); r7 = fmaf(-ss, sv3.y, r7);
        }
        __half2 h0 = __float22half2_rn(make_float2(r0, r1));
        __half2 h1 = __float22half2_rn(make_float2(r2, r3));
        __half2 h2 = __float22half2_rn(make_float2(r4, r5));
        __half2 h3 = __float22half2_rn(make_float2(r6, r7));
        uint4 uu;
        uu.x = *(unsigned int*)&h0;
        uu.y = *(unsigned int*)&h1;
        uu.z = *(unsigned int*)&h2;
        uu.w = *(unsigned int*)&h3;
        ((uint4*)dst)[o] = uu;
    }
}

// ---------------- epilogue: relu(sdeg*S + bias) -> FC -> log_softmax ----------------
__global__ __launch_bounds__(256) void final_kernel(const __half* __restrict__ S,
                                                    const float* __restrict__ sdeg,
                                                    const float* __restrict__ cheb_b,
                                                    const float* __restrict__ fc_w,
                                                    const float* __restrict__ fc_b,
                                                    float* __restrict__ out) {
    int r = blockIdx.x * blockDim.x + threadIdx.x;
    if (r >= N_NODES) return;
    float sc = sdeg[r];
    const __half2* s2 = (const __half2*)(S + (size_t)r * VROW);
    float h[D_HID];
    #pragma unroll
    for (int i = 0; i < D_HID / 2; ++i) {
        float2 f = __half22float2(s2[i]);
        float v0 = sc * f.x + cheb_b[2 * i];
        float v1 = sc * f.y + cheb_b[2 * i + 1];
        h[2 * i]     = v0 > 0.f ? v0 : 0.f;
        h[2 * i + 1] = v1 > 0.f ? v1 : 0.f;
    }
    float lg[D_OUT];
    #pragma unroll
    for (int o = 0; o < D_OUT; ++o) lg[o] = fc_b[o];
    #pragma unroll 2
    for (int i = 0; i < D_HID; ++i) {
        float hv = h[i];
        #pragma unroll
        for (int o = 0; o < D_OUT; ++o) lg[o] += hv * fc_w[i * D_OUT + o];
    }
    float mx = lg[0];
    #pragma unroll
    for (int o = 1; o < D_OUT; ++o) mx = fmaxf(mx, lg[o]);
    float s = 0.f;
    #pragma unroll
    for (int o = 0; o < D_OUT; ++o) s += __expf(lg[o] - mx);
    float ls = __logf(s);
    size_t oo = (size_t)r * D_OUT;
    #pragma unroll
    for (int o = 0; o < D_OUT; ++o) out[oo + o] = lg[o] - mx - ls;
}

extern "C" void kernel_launch(void* const* d_in, const int* in_sizes, int n_in,
                              void* d_out, int out_size, void* d_ws, size_t ws_size,
                              hipStream_t stream) {
    const float* x      = (const float*)d_in[0];
    const int*   edge   = (const int*)d_in[1];
    const float* cheb_w = (const float*)d_in[2];
    const float* cheb_b = (const float*)d_in[3];
    const float* fc_w   = (const float*)d_in[4];
    const float* fc_b   = (const float*)d_in[5];
    float* out = (float*)d_out;

    const int* erow = edge;
    const int* ecol = edge + N_EDGES;

    uintptr_t p = ((uintptr_t)d_ws + 255) & ~(uintptr_t)255;
    auto alloc = [&](size_t bytes) {
        uintptr_t q = p;
        p = (p + bytes + 255) & ~(uintptr_t)255;
        return (void*)q;
    };
    int*    row_start = (int*)alloc((size_t)(N_NODES + 1) * 4);
    float*  dinv      = (float*)alloc((size_t)(N_NODES + 1) * 4);   // +1 pad (=0)
    float*  dinv2     = (float*)alloc((size_t)N_NODES * 4);
    float*  sdeg      = (float*)alloc((size_t)N_NODES * 4);
    int*    ewc       = (int*)alloc((size_t)(N_EDGES + 32) * 4);    // +32 pad
    unsigned int* store = (unsigned int*)alloc((size_t)P1S_BLOCKS * NBUCK * BCAP * 4); // 25.2 MB
    int*    bcnt      = (int*)alloc((size_t)P1S_BLOCKS * NBUCK * 4);  // 512 KB
    __half* Wh        = (__half*)alloc((size_t)WH_ELEMS * 2);       // 80 KB
    __half* xh        = (__half*)alloc((size_t)N_NODES * D_IN * 2); // 12.8 MB
    __half* Sbuf      = (__half*)alloc(VSTRIDE * 2);                // 6.4 MB
    __half* u         = (__half*)alloc(5 * VSTRIDE * 2);            // u0..u4, 32 MB
    __half* b1        = (__half*)alloc(VSTRIDE * 2);
    __half* b3        = (__half*)alloc(VSTRIDE * 2);
    __half* b2        = (__half*)alloc(VSTRIDE * 2);
    __half* S  = Sbuf;

    // kernel A: pass1 strips (first in grid) + xh convert + Wh + pad clears
    buildA_kernel<<<P1S_BLOCKS + XH_BLOCKS + WH_BLOCKS + 1, 256, 0, stream>>>(
        erow, ecol, store, bcnt, x, cheb_w, xh, Wh, u, b1, b3, b2, dinv);

    // kernel B: pass2 CSR build (first) + vgemm u_t = x @ W_t
    buildB_kernel<<<NB_USED + VGB_BLOCKS, 512, 0, stream>>>(
        store, bcnt, row_start, dinv, dinv2, sdeg, ewc, xh, Wh, u);

    __half* u0 = u;
    __half* u1 = u + 1 * VSTRIDE;
    __half* u2 = u + 2 * VSTRIDE;
    __half* u3 = u + 3 * VSTRIDE;
    __half* u4 = u + 4 * VSTRIDE;
    const int PB = N_NODES / 8;   // 6250 blocks x 8 waves
    // b3 = dinv.*u3 + 2M(dinv.*u4)
    prop_kernel<1, 0, 0><<<PB, 512, 0, stream>>>(row_start, ewc, dinv2, dinv,
                                                 u4, u3, u3, 2.f, b3);
    // b2 = dinv.*u2 + 2M b3 - dinv.*u4
    prop_kernel<0, 1, 1><<<PB, 512, 0, stream>>>(row_start, ewc, dinv2, dinv,
                                                 b3, u2, u4, 2.f, b2);
    // b1 = dinv.*u1 + 2M b2 - b3
    prop_kernel<0, 1, 0><<<PB, 512, 0, stream>>>(row_start, ewc, dinv2, dinv,
                                                 b2, u1, b3, 2.f, b1);
    // S = dinv.*u0 + M b1 - b2
    prop_kernel<0, 1, 0><<<PB, 512, 0, stream>>>(row_start, ewc, dinv2, dinv,
                                                 b1, u0, b2, 1.f, S);

    // out = log_softmax(relu(sdeg*S + bias) @ fc_w + fc_b)
    final_kernel<<<(N_NODES + 255) / 256, 256, 0, stream>>>(S, sdeg, cheb_b,
                                                            fc_w, fc_b, out);
}